// Round 7
// baseline (1846.146 us; speedup 1.0000x reference)
//
#include <hip/hip_runtime.h>
#include <cstdint>
#include <cstddef>

// Problem constants (fixed by the reference).
constexpr int Bn = 2048, Ln = 128, Cn = 32, Hn = 64, On = 16;
constexpr int NIv = Ln - 1;                       // 127 intervals
constexpr float K2 = 2.885390081777927f;          // 2*log2(e): tanh(x)=1-2/(1+exp2(K2*x))

__device__ __forceinline__ float fexp2(float x) {
#if __has_builtin(__builtin_amdgcn_exp2f)
  return __builtin_amdgcn_exp2f(x);
#else
  float r; asm("v_exp_f32 %0, %1" : "=v"(r) : "v"(x)); return r;
#endif
}
__device__ __forceinline__ float frcpf(float x) {
#if __has_builtin(__builtin_amdgcn_rcpf)
  return __builtin_amdgcn_rcpf(x);
#else
  float r; asm("v_rcp_f32 %0, %1" : "=v"(r) : "v"(x)); return r;
#endif
}
__device__ __forceinline__ float tanh_fast(float x) {
  float e = fexp2(K2 * x);
  return fmaf(-2.0f, frcpf(e + 1.0f), 1.0f);
}

// DPP add step (full-rate VALU, no LDS). Masked lanes keep old=0 -> p+0.
template<int CTRL, int RMASK>
__device__ __forceinline__ float dpp_addstep(float p) {
  int q = __builtin_amdgcn_update_dpp(0, __float_as_int(p), CTRL, RMASK, 0xF, true);
  return p + __int_as_float(q);
}
// Full 64-lane sum: 4 xor-steps within rows + row_bcast15 + row_bcast31,
// total lands in lane 63; returned as a wave-uniform scalar via readlane.
__device__ __forceinline__ float fullsum64(float p) {
  p = dpp_addstep<0xB1, 0xF>(p);     // quad_perm [1,0,3,2]
  p = dpp_addstep<0x4E, 0xF>(p);     // quad_perm [2,3,0,1]
  p = dpp_addstep<0x141, 0xF>(p);    // row_half_mirror
  p = dpp_addstep<0x140, 0xF>(p);    // row_mirror -> each 16-row holds rowsum
  p = dpp_addstep<0x142, 0xA>(p);    // row_bcast15 -> rows 1,3 = pair sums
  p = dpp_addstep<0x143, 0xC>(p);    // row_bcast31 -> row 3 = total
  return __int_as_float(__builtin_amdgcn_readlane(__float_as_int(p), 63));
}

// ---------------------------------------------------------------------------
// Kernel 1: sequential RK4 scan. One 64-thread block = one wave = one batch
// element; lane = h. r5's C-split reverted (per-stage barrier exchange cost
// ~1600 cyc/interval). Weights pre-scaled by K2 in NAMED floats, pinned
// register-resident with an opaque asm (defeats 4 rounds of remat).
// Per-element work: u=2 fma, exp2, add, rcp, fma(r*d) -> 4 VALU + 2 trans;
// the tanh identity sum Σ(1-2r)d = Σd - 2Σrd uses per-interval DPP-reduced
// channel sums (lane-uniform), removing one fma per element.
// ---------------------------------------------------------------------------
#define REP8(M) M(0) M(1) M(2) M(3) M(4) M(5) M(6) M(7)

__global__ __launch_bounds__(64, 2) void ncde_scan_kernel(
    const float* __restrict__ coeffs, const float* __restrict__ t,
    const float* __restrict__ W_init, const float* __restrict__ b_init,
    const float* __restrict__ W1, const float* __restrict__ b1,
    const float* __restrict__ W2, const float* __restrict__ b2,
    float* __restrict__ zt)
{
  __shared__ alignas(16) float sdx[5][32];   // [s-index][c], per-wave private
  const int lane = threadIdx.x;              // 0..63 = h
  const int b = blockIdx.x;

  const float w10 = W1[2 * lane], w11 = W1[2 * lane + 1];
  const float sb0 = b1[0], sb1 = b1[1];

  // Weights: A=K2*w20[c], B=K2*w21[c], C=K2*b2[c] for this lane's h.
#define DECLW(g) float Ax##g, Ay##g, Az##g, Aw##g, \
                       Bx##g, By##g, Bz##g, Bw##g, \
                       Cx##g, Cy##g, Cz##g, Cw##g;
  REP8(DECLW)
  {
    const float* W2a = W2 + lane * 32;
    const float* W2b = W2 + 2048 + lane * 32;
    const float* b2a = b2 + lane * 32;
#define LOADW(g) { \
      const float4 x0 = *(const float4*)(W2a + 4 * (g)); \
      const float4 x1 = *(const float4*)(W2b + 4 * (g)); \
      const float4 x2 = *(const float4*)(b2a + 4 * (g)); \
      Ax##g = x0.x * K2; Ay##g = x0.y * K2; Az##g = x0.z * K2; Aw##g = x0.w * K2; \
      Bx##g = x1.x * K2; By##g = x1.y * K2; Bz##g = x1.z * K2; Bw##g = x1.w * K2; \
      Cx##g = x2.x * K2; Cy##g = x2.y * K2; Cz##g = x2.z * K2; Cw##g = x2.w * K2; }
    REP8(LOADW)
    // Opaque pin: defs become non-rematerializable -> must stay live in VGPRs.
#define PINW(g) asm("" : "+v"(Ax##g), "+v"(Ay##g), "+v"(Az##g), "+v"(Aw##g), \
                         "+v"(Bx##g), "+v"(By##g), "+v"(Bz##g), "+v"(Bw##g), \
                         "+v"(Cx##g), "+v"(Cy##g), "+v"(Cz##g), "+v"(Cw##g));
    REP8(PINW)
  }

  // z0 = X0 @ W_init + b_init, X0 = a-part of interval 0.
  const float* cb0 = coeffs + (size_t)b * NIv * 128;
  if (lane < 32) sdx[0][lane] = cb0[lane];
  __builtin_amdgcn_wave_barrier();
  float z = b_init[lane];
#pragma unroll 4
  for (int c = 0; c < 32; ++c)
    z = fmaf(sdx[0][c], W_init[(c << 6) + lane], z);
  zt[(size_t)b * Ln * Hn + lane] = tanh_fast(z);

#pragma unroll 1
  for (int i = 0; i < NIv; ++i) {
    const float* cb = cb0 + (size_t)i * 128;
    const float dti = t[i + 1] - t[i];
    const float hst = 0.5f * dti;
    const float q = 0.25f * dti;
    const int lc = lane & 31;
    // All 64 lanes load the 32 b/c/d channel values (2x duplicated).
    const float bv = cb[32 + lc];
    const float cv = cb[64 + lc];
    const float dv = cb[96 + lc];
    __builtin_amdgcn_wave_barrier();     // prior-stage sdx reads precede overwrite
    if (lane < 32) {
#pragma unroll
      for (int k = 0; k < 5; ++k) {
        const float s = q * (float)k;
        sdx[k][lc] = fmaf(fmaf(dv, s, cv), s, bv);
      }
    }
    // Channel sums (64-lane sum = 2x the 32-channel sum -> 0.5 factor).
    const float Sb = fullsum64(bv);
    const float Sc = fullsum64(cv);
    const float Sd = fullsum64(dv);
#define SUMK(s_) (0.5f * fmaf((s_), fmaf((s_), Sd, Sc), Sb))
    const float sm0 = 0.5f * Sb;
    const float sm1 = SUMK(q);
    const float sm2 = SUMK(2.0f * q);
    const float sm3 = SUMK(3.0f * q);
    const float sm4 = SUMK(4.0f * q);
    __builtin_amdgcn_wave_barrier();

    float kacc = 0.0f, kprev = 0.0f;
#pragma unroll
    for (int j = 0; j < 2; ++j) {          // N_SUB substeps
      if (j == 1) { z = fmaf(hst * (1.0f / 6.0f), kacc, z); kacc = 0.0f; kprev = 0.0f; }
#pragma unroll
      for (int st = 0; st < 4; ++st) {     // RK4 stages
        const float cin = (st == 0) ? 0.0f : (st == 3) ? hst : 0.5f * hst;
        const float wgt = (st == 1 || st == 2) ? 2.0f : 1.0f;
        const int kidx = 2 * j + ((st + 1) >> 1);          // compile-time 0..4
        const float smk = (kidx == 0) ? sm0 : (kidx == 1) ? sm1
                        : (kidx == 2) ? sm2 : (kidx == 3) ? sm3 : sm4;
        const float* dxp = &sdx[kidx][0];
        const float zs = fmaf(cin, kprev, z);
        // h1 = relu(zs @ W1 + b1): two DPP full-sums.
        const float h10 = fmaxf(fullsum64(zs * w10) + sb0, 0.0f);
        const float h11 = fmaxf(fullsum64(zs * w11) + sb1, 0.0f);
        float a0 = 0.0f, a1 = 0.0f, a2 = 0.0f, a3 = 0.0f;
#define GRP(g) { \
        const float4 d4 = *(const float4*)(dxp + 4 * (g)); \
        const float u0 = fmaf(Ax##g, h10, fmaf(Bx##g, h11, Cx##g)); \
        const float u1 = fmaf(Ay##g, h10, fmaf(By##g, h11, Cy##g)); \
        const float u2 = fmaf(Az##g, h10, fmaf(Bz##g, h11, Cz##g)); \
        const float u3 = fmaf(Aw##g, h10, fmaf(Bw##g, h11, Cw##g)); \
        const float r0 = frcpf(fexp2(u0) + 1.0f); \
        const float r1 = frcpf(fexp2(u1) + 1.0f); \
        const float r2 = frcpf(fexp2(u2) + 1.0f); \
        const float r3 = frcpf(fexp2(u3) + 1.0f); \
        a0 = fmaf(r0, d4.x, a0); \
        a1 = fmaf(r1, d4.y, a1); \
        a2 = fmaf(r2, d4.z, a2); \
        a3 = fmaf(r3, d4.w, a3); }
        REP8(GRP)
        const float acc = fmaf(-2.0f, (a0 + a1) + (a2 + a3), smk);
        kprev = acc;
        kacc = fmaf(wgt, acc, kacc);
      }
    }
    z = fmaf(hst * (1.0f / 6.0f), kacc, z);
    zt[((size_t)b * Ln + (i + 1)) * Hn + lane] = tanh_fast(z);
  }
}

// ---------------------------------------------------------------------------
// Kernel 2: readout + hermite coeffs. One block per batch element.
// ---------------------------------------------------------------------------
#define SPX(l_, o_) (((l_) << 4) | (((o_) + (l_)) & 15))
#define SZX(l_, h_) (((l_) << 6) | (((h_) + (l_)) & 63))

__global__ __launch_bounds__(128, 2) void ncde_epilogue_kernel(
    const float* __restrict__ zt, const float* __restrict__ t,
    const float* __restrict__ W_read, const float* __restrict__ b_read,
    float* __restrict__ out)
{
  __shared__ float sW[Hn * On];
  __shared__ float sz[Ln * Hn];
  __shared__ float sp[Ln * On];
  __shared__ float st_[Ln];
  const int b = blockIdx.x;
  const int tid = threadIdx.x;

  for (int i2 = tid; i2 < Hn * On; i2 += 128) sW[i2] = W_read[i2];
  st_[tid] = t[tid];
  const float* zb = zt + (size_t)b * Ln * Hn;
#pragma unroll 1
  for (int r = 0; r < 16; ++r) {
    const int base = (r * 128 + tid) * 4;       // 8192 floats, float4-granular
    const float4 v = *(const float4*)(zb + base);
    const int l = base >> 6, h = base & 63;     // h multiple of 4, no row wrap
    sz[SZX(l, h + 0)] = v.x;
    sz[SZX(l, h + 1)] = v.y;
    sz[SZX(l, h + 2)] = v.z;
    sz[SZX(l, h + 3)] = v.w;
  }
  __syncthreads();

  // Readout: thread tid owns row l = tid, all 16 outputs in registers.
  float acc0[On];
#pragma unroll
  for (int o = 0; o < On; ++o) acc0[o] = b_read[o];
#pragma unroll 2
  for (int h = 0; h < Hn; ++h) {
    const float zv = sz[SZX(tid, h)];
#pragma unroll
    for (int o = 0; o < On; ++o) acc0[o] = fmaf(zv, sW[h * On + o], acc0[o]);
  }
  float* po = out + ((size_t)b * Ln + tid) * On;
#pragma unroll
  for (int o = 0; o < On; ++o) sp[SPX(tid, o)] = acc0[o];
#pragma unroll
  for (int o4 = 0; o4 < 4; ++o4) {
    float4 v = make_float4(acc0[4*o4], acc0[4*o4+1], acc0[4*o4+2], acc0[4*o4+3]);
    *(float4*)(po + 4 * o4) = v;
  }
  __syncthreads();

  // Hermite coefficients of pred_y: a = p_i, b = d0, 2c, 3d (per o).
  float* cbo = out + (size_t)Bn * Ln * On + (size_t)b * NIv * 64;
#pragma unroll 1
  for (int r = 0; r < 16; ++r) {
    const int item = r * 128 + tid;
    if (item < NIv * On) {
      const int i = item >> 4, o = item & 15;
      const float p0 = sp[SPX(i, o)], p1 = sp[SPX(i + 1, o)];
      const float rdt = frcpf(st_[i + 1] - st_[i]);
      const float si = (p1 - p0) * rdt;
      float d0;
      if (i == 0) d0 = si;
      else d0 = (p0 - sp[SPX(i - 1, o)]) * frcpf(st_[i] - st_[i - 1]);
      const float d1 = si;
      float* cc = cbo + (size_t)i * 64 + o;
      cc[0]  = p0;
      cc[16] = d0;
      cc[32] = 2.0f * (3.0f * si - 2.0f * d0 - d1) * rdt;
      cc[48] = 3.0f * (d0 + d1 - 2.0f * si) * (rdt * rdt);
    }
  }
}

extern "C" void kernel_launch(void* const* d_in, const int* in_sizes, int n_in,
                              void* d_out, int out_size, void* d_ws, size_t ws_size,
                              hipStream_t stream) {
  const float* coeffs = (const float*)d_in[0];
  const float* t      = (const float*)d_in[1];
  const float* W_init = (const float*)d_in[2];
  const float* b_init = (const float*)d_in[3];
  const float* W1     = (const float*)d_in[4];
  const float* b1     = (const float*)d_in[5];
  const float* W2     = (const float*)d_in[6];
  const float* b2     = (const float*)d_in[7];
  const float* W_read = (const float*)d_in[8];
  const float* b_read = (const float*)d_in[9];
  float* out = (float*)d_out;
  float* zt  = (float*)d_ws;   // needs B*L*H*4 = 64 MiB of scratch

  ncde_scan_kernel<<<dim3(Bn), dim3(64), 0, stream>>>(
      coeffs, t, W_init, b_init, W1, b1, W2, b2, zt);
  ncde_epilogue_kernel<<<dim3(Bn), dim3(128), 0, stream>>>(
      zt, t, W_read, b_read, out);
}